// Round 2
// baseline (2425.552 us; speedup 1.0000x reference)
//
#include <hip/hip_runtime.h>
#include <hip/hip_bf16.h>
#include <cmath>

#define NL 16
#define TSIZE (1u << 19)
#define TMASK (TSIZE - 1u)

struct LevelParams {
  float scale[NL];
  unsigned res[NL];
  unsigned dense_mask;
};

// ---------------- Kernel 1: hash-grid encode, one thread per (ray, level) ----
__global__ __launch_bounds__(256)
void encode_k(const float* __restrict__ dirs,
              const float* __restrict__ table,
              __hip_bfloat162* __restrict__ feat_out,
              int n, LevelParams lp)
{
  int tid = blockIdx.x * 256 + threadIdx.x;
  int ray = tid >> 4;
  int l   = tid & 15;
  if (ray >= n) return;

  float dx = dirs[ray * 3 + 0];
  float dy = dirs[ray * 3 + 1];
  float dz = dirs[ray * 3 + 2];
  float xx = dx * 0.49f + 0.49f;
  float xy = dy * 0.49f + 0.49f;
  float xz = dz * 0.49f + 0.49f;

  // select this lane's level params (wave-uniform values, lane-divergent index
  // -> cndmask tree, no scratch)
  float s = 0.0f; unsigned r = 0; bool dense = false;
  #pragma unroll
  for (int k = 0; k < NL; ++k) {
    if (l == k) { s = lp.scale[k]; r = lp.res[k]; dense = (lp.dense_mask >> k) & 1u; }
  }

  float px = xx * s + 0.5f, py = xy * s + 0.5f, pz = xz * s + 0.5f;
  float gx = floorf(px), gy = floorf(py), gz = floorf(pz);
  float fx = px - gx, fy = py - gy, fz = pz - gz;
  unsigned ix = (unsigned)gx, iy = (unsigned)gy, iz = (unsigned)gz;

  float wx1 = fx * fx * (3.0f - 2.0f * fx);
  float wy1 = fy * fy * (3.0f - 2.0f * fy);
  float wz1 = fz * fz * (3.0f - 2.0f * fz);
  float wx0 = 1.0f - wx1, wy0 = 1.0f - wy1, wz0 = 1.0f - wz1;

  unsigned i000, i100, i010, i110, i001, i101, i011, i111;
  if (dense) {
    unsigned r2 = r * r;
    unsigned x0 = ix, x1 = ix + 1u;
    unsigned y0 = iy * r, y1 = y0 + r;
    unsigned z0 = iz * r2, z1 = z0 + r2;
    i000 = x0 + y0 + z0; i100 = x1 + y0 + z0;
    i010 = x0 + y1 + z0; i110 = x1 + y1 + z0;
    i001 = x0 + y0 + z1; i101 = x1 + y0 + z1;
    i011 = x0 + y1 + z1; i111 = x1 + y1 + z1;
  } else {
    unsigned x0 = ix, x1 = ix + 1u;
    unsigned y0 = iy * 2654435761u, y1 = y0 + 2654435761u;  // uint32 wrap == ref
    unsigned z0 = iz * 805459861u,  z1 = z0 + 805459861u;
    i000 = (x0 ^ y0 ^ z0) & TMASK; i100 = (x1 ^ y0 ^ z0) & TMASK;
    i010 = (x0 ^ y1 ^ z0) & TMASK; i110 = (x1 ^ y1 ^ z0) & TMASK;
    i001 = (x0 ^ y0 ^ z1) & TMASK; i101 = (x1 ^ y0 ^ z1) & TMASK;
    i011 = (x0 ^ y1 ^ z1) & TMASK; i111 = (x1 ^ y1 ^ z1) & TMASK;
  }

  const float2* t = (const float2*)table + (size_t)l * TSIZE;
  float2 f000 = t[i000], f100 = t[i100], f010 = t[i010], f110 = t[i110];
  float2 f001 = t[i001], f101 = t[i101], f011 = t[i011], f111 = t[i111];

  float wy0z0 = wy0 * wz0, wy1z0 = wy1 * wz0, wy0z1 = wy0 * wz1, wy1z1 = wy1 * wz1;
  float w000 = wx0 * wy0z0, w100 = wx1 * wy0z0;
  float w010 = wx0 * wy1z0, w110 = wx1 * wy1z0;
  float w001 = wx0 * wy0z1, w101 = wx1 * wy0z1;
  float w011 = wx0 * wy1z1, w111 = wx1 * wy1z1;

  float a0 = w000 * f000.x + w100 * f100.x + w010 * f010.x + w110 * f110.x
           + w001 * f001.x + w101 * f101.x + w011 * f011.x + w111 * f111.x;
  float a1 = w000 * f000.y + w100 * f100.y + w010 * f010.y + w110 * f110.y
           + w001 * f001.y + w101 * f101.y + w011 * f011.y + w111 * f111.y;

  feat_out[tid] = __hip_bfloat162(__float2bfloat16(a0), __float2bfloat16(a1));
}

// ---------------- Kernel 2: MLP 35->64->64->1 + softplus, one thread/ray -----
__device__ __forceinline__ void unpack_bf16x2(unsigned u, float& lo, float& hi) {
  union { unsigned u; float f; } a, b;
  a.u = u << 16;          // low bf16
  b.u = u & 0xffff0000u;  // high bf16
  lo = a.f; hi = b.f;
}

__global__ __launch_bounds__(256)
void mlp_k(const float* __restrict__ dirs,
           const uint4* __restrict__ feats,   // [n][4] uint4 = 16 levels x 2 bf16
           const float* __restrict__ W1, const float* __restrict__ b1,
           const float* __restrict__ W2, const float* __restrict__ b2,
           const float* __restrict__ W3, const float* __restrict__ b3,
           float* __restrict__ out, int n)
{
  int gid = blockIdx.x * 256 + threadIdx.x;
  if (gid >= n) return;

  float h[35];
  h[0] = dirs[gid * 3 + 0];
  h[1] = dirs[gid * 3 + 1];
  h[2] = dirs[gid * 3 + 2];

  #pragma unroll
  for (int q = 0; q < 4; ++q) {
    uint4 v = feats[gid * 4 + q];
    unpack_bf16x2(v.x, h[3 + q * 8 + 0], h[3 + q * 8 + 1]);
    unpack_bf16x2(v.y, h[3 + q * 8 + 2], h[3 + q * 8 + 3]);
    unpack_bf16x2(v.z, h[3 + q * 8 + 4], h[3 + q * 8 + 5]);
    unpack_bf16x2(v.w, h[3 + q * 8 + 6], h[3 + q * 8 + 7]);
  }

  float h1[64];
  #pragma unroll
  for (int j = 0; j < 64; ++j) {
    float acc = b1[j];
    #pragma unroll
    for (int i = 0; i < 35; ++i) acc = fmaf(h[i], W1[i * 64 + j], acc);
    h1[j] = fmaxf(acc, 0.0f);
  }

  float h2[64];
  #pragma unroll
  for (int j = 0; j < 64; ++j) {
    float acc = b2[j];
    #pragma unroll
    for (int i = 0; i < 64; ++i) acc = fmaf(h1[i], W2[i * 64 + j], acc);
    h2[j] = fmaxf(acc, 0.0f);
  }

  float o = b3[0];
  #pragma unroll
  for (int i = 0; i < 64; ++i) o = fmaf(h2[i], W3[i], o);

  float v = o + 1.0f;
  out[gid] = fmaxf(v, 0.0f) + log1pf(expf(-fabsf(v)));  // softplus(v)
}

// ---------------- Fallback: round-1 fused kernel (if ws too small) -----------
__global__ __launch_bounds__(256)
void sdf_fused(const float* __restrict__ dirs,
               const float* __restrict__ table,
               const float* __restrict__ W1, const float* __restrict__ b1,
               const float* __restrict__ W2, const float* __restrict__ b2,
               const float* __restrict__ W3, const float* __restrict__ b3,
               float* __restrict__ out, int n, LevelParams lp)
{
  int gid = blockIdx.x * 256 + threadIdx.x;
  if (gid >= n) return;

  float dx = dirs[gid * 3 + 0];
  float dy = dirs[gid * 3 + 1];
  float dz = dirs[gid * 3 + 2];
  float xx = dx * 0.49f + 0.49f;
  float xy = dy * 0.49f + 0.49f;
  float xz = dz * 0.49f + 0.49f;

  float h[35];
  h[0] = dx; h[1] = dy; h[2] = dz;

  #pragma unroll
  for (int l = 0; l < NL; ++l) {
    float s = lp.scale[l];
    float px = xx * s + 0.5f, py = xy * s + 0.5f, pz = xz * s + 0.5f;
    float gx = floorf(px), gy = floorf(py), gz = floorf(pz);
    float fx = px - gx, fy = py - gy, fz = pz - gz;
    unsigned ix = (unsigned)gx, iy = (unsigned)gy, iz = (unsigned)gz;

    float wx1 = fx * fx * (3.0f - 2.0f * fx);
    float wy1 = fy * fy * (3.0f - 2.0f * fy);
    float wz1 = fz * fz * (3.0f - 2.0f * fz);
    float wx0 = 1.0f - wx1, wy0 = 1.0f - wy1, wz0 = 1.0f - wz1;

    unsigned i000, i100, i010, i110, i001, i101, i011, i111;
    if ((lp.dense_mask >> l) & 1u) {
      unsigned r = lp.res[l];
      unsigned r2 = r * r;
      unsigned x0 = ix, x1 = ix + 1u;
      unsigned y0 = iy * r, y1 = y0 + r;
      unsigned z0 = iz * r2, z1 = z0 + r2;
      i000 = x0 + y0 + z0; i100 = x1 + y0 + z0;
      i010 = x0 + y1 + z0; i110 = x1 + y1 + z0;
      i001 = x0 + y0 + z1; i101 = x1 + y0 + z1;
      i011 = x0 + y1 + z1; i111 = x1 + y1 + z1;
    } else {
      unsigned x0 = ix, x1 = ix + 1u;
      unsigned y0 = iy * 2654435761u, y1 = y0 + 2654435761u;
      unsigned z0 = iz * 805459861u,  z1 = z0 + 805459861u;
      i000 = (x0 ^ y0 ^ z0) & TMASK; i100 = (x1 ^ y0 ^ z0) & TMASK;
      i010 = (x0 ^ y1 ^ z0) & TMASK; i110 = (x1 ^ y1 ^ z0) & TMASK;
      i001 = (x0 ^ y0 ^ z1) & TMASK; i101 = (x1 ^ y0 ^ z1) & TMASK;
      i011 = (x0 ^ y1 ^ z1) & TMASK; i111 = (x1 ^ y1 ^ z1) & TMASK;
    }

    const float2* t = (const float2*)table + (size_t)l * TSIZE;
    float2 f000 = t[i000], f100 = t[i100], f010 = t[i010], f110 = t[i110];
    float2 f001 = t[i001], f101 = t[i101], f011 = t[i011], f111 = t[i111];

    float wy0z0 = wy0 * wz0, wy1z0 = wy1 * wz0, wy0z1 = wy0 * wz1, wy1z1 = wy1 * wz1;
    float w000 = wx0 * wy0z0, w100 = wx1 * wy0z0;
    float w010 = wx0 * wy1z0, w110 = wx1 * wy1z0;
    float w001 = wx0 * wy0z1, w101 = wx1 * wy0z1;
    float w011 = wx0 * wy1z1, w111 = wx1 * wy1z1;

    float a0 = w000 * f000.x + w100 * f100.x + w010 * f010.x + w110 * f110.x
             + w001 * f001.x + w101 * f101.x + w011 * f011.x + w111 * f111.x;
    float a1 = w000 * f000.y + w100 * f100.y + w010 * f010.y + w110 * f110.y
             + w001 * f001.y + w101 * f101.y + w011 * f011.y + w111 * f111.y;
    h[3 + 2 * l] = a0;
    h[4 + 2 * l] = a1;
  }

  float h1[64];
  #pragma unroll
  for (int j = 0; j < 64; ++j) {
    float acc = b1[j];
    #pragma unroll
    for (int i = 0; i < 35; ++i) acc = fmaf(h[i], W1[i * 64 + j], acc);
    h1[j] = fmaxf(acc, 0.0f);
  }

  float h2[64];
  #pragma unroll
  for (int j = 0; j < 64; ++j) {
    float acc = b2[j];
    #pragma unroll
    for (int i = 0; i < 64; ++i) acc = fmaf(h1[i], W2[i * 64 + j], acc);
    h2[j] = fmaxf(acc, 0.0f);
  }

  float o = b3[0];
  #pragma unroll
  for (int i = 0; i < 64; ++i) o = fmaf(h2[i], W3[i], o);

  float v = o + 1.0f;
  out[gid] = fmaxf(v, 0.0f) + log1pf(expf(-fabsf(v)));
}

extern "C" void kernel_launch(void* const* d_in, const int* in_sizes, int n_in,
                              void* d_out, int out_size, void* d_ws, size_t ws_size,
                              hipStream_t stream) {
  const float* dirs  = (const float*)d_in[0];
  const float* table = (const float*)d_in[1];
  const float* W1 = (const float*)d_in[2];
  const float* b1 = (const float*)d_in[3];
  const float* W2 = (const float*)d_in[4];
  const float* b2 = (const float*)d_in[5];
  const float* W3 = (const float*)d_in[6];
  const float* b3 = (const float*)d_in[7];
  float* out = (float*)d_out;
  int n = in_sizes[0] / 3;

  LevelParams lp;
  double pls = std::exp(std::log(2048.0 / 16.0) / 15.0);
  unsigned dm = 0;
  for (int l = 0; l < NL; ++l) {
    double scale = 16.0 * std::pow(pls, (double)l) - 1.0;
    lp.scale[l] = (float)scale;
    long long res = (long long)std::ceil(scale) + 1;
    lp.res[l] = (unsigned)res;
    if (res * res * res <= (long long)TSIZE) dm |= (1u << l);
  }
  lp.dense_mask = dm;

  size_t feat_bytes = (size_t)n * NL * sizeof(__hip_bfloat162);  // 128 MiB
  if (ws_size >= feat_bytes) {
    __hip_bfloat162* feats = (__hip_bfloat162*)d_ws;
    int enc_blocks = (n * NL + 255) / 256;
    hipLaunchKernelGGL(encode_k, dim3(enc_blocks), dim3(256), 0, stream,
                       dirs, table, feats, n, lp);
    int mlp_blocks = (n + 255) / 256;
    hipLaunchKernelGGL(mlp_k, dim3(mlp_blocks), dim3(256), 0, stream,
                       dirs, (const uint4*)feats, W1, b1, W2, b2, W3, b3, out, n);
  } else {
    int blocks = (n + 255) / 256;
    hipLaunchKernelGGL(sdf_fused, dim3(blocks), dim3(256), 0, stream,
                       dirs, table, W1, b1, W2, b2, W3, b3, out, n, lp);
  }
}

// Round 4
// 1164.939 us; speedup vs baseline: 2.0821x; 2.0821x over previous
//
#include <hip/hip_runtime.h>
#include <hip/hip_bf16.h>
#include <cmath>

#define NL 16
#define TSIZE (1u << 19)
#define TMASK (TSIZE - 1u)

typedef __attribute__((ext_vector_type(8))) short bf16x8;     // 8 bf16 (4 VGPRs)
typedef __attribute__((ext_vector_type(4))) float f32x4;

struct LevelParams {
  float scale[NL];
  unsigned res[NL];
  unsigned dense_mask;
};

static __device__ __forceinline__ short f2bf(float f) {
  __hip_bfloat16 h = __float2bfloat16(f);
  return *reinterpret_cast<short*>(&h);
}
static __device__ __forceinline__ short lo16(unsigned u) { return (short)(u & 0xffffu); }
static __device__ __forceinline__ short hi16(unsigned u) { return (short)(u >> 16); }

// ============ Kernel 1: encode. One LEVEL per block, XCD-pinned. ============
// blockIdx%8 -> XCD (empirical round-robin); levels (k, k+8) pinned to XCD k
// => per-XCD L2 working set 4-8 MB instead of 46 MB.
// Output level-major: ws[l*n + ray] (coalesced 4B stores).
__global__ __launch_bounds__(256)
void encode_k2(const float* __restrict__ dirs,
               const float* __restrict__ table,
               unsigned* __restrict__ ws,
               int n, LevelParams lp)
{
  int b = blockIdx.x;
  int level = (b & 7) + 8 * ((b >> 3) & 1);   // block-uniform
  int chunk = b >> 4;
  int ray = chunk * 256 + threadIdx.x;
  if (ray >= n) return;

  float dx = dirs[ray * 3 + 0];
  float dy = dirs[ray * 3 + 1];
  float dz = dirs[ray * 3 + 2];
  float xx = dx * 0.49f + 0.49f;
  float xy = dy * 0.49f + 0.49f;
  float xz = dz * 0.49f + 0.49f;

  float s = lp.scale[level];
  unsigned r = lp.res[level];
  bool dense = (lp.dense_mask >> level) & 1u;

  float px = xx * s + 0.5f, py = xy * s + 0.5f, pz = xz * s + 0.5f;
  float gx = floorf(px), gy = floorf(py), gz = floorf(pz);
  float fx = px - gx, fy = py - gy, fz = pz - gz;
  unsigned ix = (unsigned)gx, iy = (unsigned)gy, iz = (unsigned)gz;

  float wx1 = fx * fx * (3.0f - 2.0f * fx);
  float wy1 = fy * fy * (3.0f - 2.0f * fy);
  float wz1 = fz * fz * (3.0f - 2.0f * fz);
  float wx0 = 1.0f - wx1, wy0 = 1.0f - wy1, wz0 = 1.0f - wz1;

  unsigned i000, i100, i010, i110, i001, i101, i011, i111;
  if (dense) {
    unsigned r2 = r * r;
    unsigned x0 = ix, x1 = ix + 1u;
    unsigned y0 = iy * r, y1 = y0 + r;
    unsigned z0 = iz * r2, z1 = z0 + r2;
    i000 = x0 + y0 + z0; i100 = x1 + y0 + z0;
    i010 = x0 + y1 + z0; i110 = x1 + y1 + z0;
    i001 = x0 + y0 + z1; i101 = x1 + y0 + z1;
    i011 = x0 + y1 + z1; i111 = x1 + y1 + z1;
  } else {
    unsigned x0 = ix, x1 = ix + 1u;
    unsigned y0 = iy * 2654435761u, y1 = y0 + 2654435761u;  // uint32 wrap == ref
    unsigned z0 = iz * 805459861u,  z1 = z0 + 805459861u;
    i000 = (x0 ^ y0 ^ z0) & TMASK; i100 = (x1 ^ y0 ^ z0) & TMASK;
    i010 = (x0 ^ y1 ^ z0) & TMASK; i110 = (x1 ^ y1 ^ z0) & TMASK;
    i001 = (x0 ^ y0 ^ z1) & TMASK; i101 = (x1 ^ y0 ^ z1) & TMASK;
    i011 = (x0 ^ y1 ^ z1) & TMASK; i111 = (x1 ^ y1 ^ z1) & TMASK;
  }

  const float2* t = (const float2*)table + (size_t)level * TSIZE;
  float2 f000 = t[i000], f100 = t[i100], f010 = t[i010], f110 = t[i110];
  float2 f001 = t[i001], f101 = t[i101], f011 = t[i011], f111 = t[i111];

  float wy0z0 = wy0 * wz0, wy1z0 = wy1 * wz0, wy0z1 = wy0 * wz1, wy1z1 = wy1 * wz1;
  float w000 = wx0 * wy0z0, w100 = wx1 * wy0z0;
  float w010 = wx0 * wy1z0, w110 = wx1 * wy1z0;
  float w001 = wx0 * wy0z1, w101 = wx1 * wy0z1;
  float w011 = wx0 * wy1z1, w111 = wx1 * wy1z1;

  float a0 = w000 * f000.x + w100 * f100.x + w010 * f010.x + w110 * f110.x
           + w001 * f001.x + w101 * f101.x + w011 * f011.x + w111 * f111.x;
  float a1 = w000 * f000.y + w100 * f100.y + w010 * f010.y + w110 * f110.y
           + w001 * f001.y + w101 * f101.y + w011 * f011.y + w111 * f111.y;

  unsigned packed = ((unsigned)f2bf(a0) & 0xffffu) | (((unsigned)f2bf(a1) & 0xffffu) << 16);
  ws[(size_t)level * n + ray] = packed;
}

// ============ Kernel 2: MLP via bf16 MFMA (16x16x32), fp32 accumulate. ======
// Block = 256 thr = 4 waves; each wave owns 16 rays/batch; 8 batches/block.
// Layouts (m89/m120-verified): A[m=lane&15][k=q*8+j] (q=lane>>4);
// B frag from B^T rows [n][k]; C/D col=lane&15, row=q*4+reg.
// NOTE: every cross-lane LDS hand-off is fenced with __syncthreads() — the
// per-thread address sets of the write and read phases are disjoint, so
// without a barrier the compiler may legally hoist the reads above ALL the
// writes (that was round 3's 1e37 bug: fragments read virgin LDS).
#define RPB 512
#define ROWS 72   // padded row stride in shorts (144 B = 16B-aligned)

__global__ __launch_bounds__(256)
void mlp_mfma(const float* __restrict__ dirs,
              const unsigned* __restrict__ ws,   // [16][n] bf16x2 level-major
              const float* __restrict__ W1, const float* __restrict__ b1,
              const float* __restrict__ W2, const float* __restrict__ b2,
              const float* __restrict__ W3, const float* __restrict__ b3,
              float* __restrict__ out, int n)
{
  __shared__ short W1T[64 * ROWS];      // B^T: [n][k] bf16, k padded 35->64
  __shared__ short W2T[64 * ROWS];
  __shared__ short AT[4][16 * ROWS];    // per-wave A tile [16 rays][64 k]
  __shared__ short H1T[4][16 * ROWS];   // per-wave hidden tile

  int tid = threadIdx.x;
  // ---- stage weights (once per block) ----
  {
    int nn = tid >> 2;          // output neuron 0..63
    int kg = tid & 3;           // k-group of 16
    bf16x8 v1a = {0,0,0,0,0,0,0,0}, v1b = {0,0,0,0,0,0,0,0};
    bf16x8 v2a = {0,0,0,0,0,0,0,0}, v2b = {0,0,0,0,0,0,0,0};
    #pragma unroll
    for (int j = 0; j < 8; ++j) {
      int k0 = kg * 16 + j, k1 = kg * 16 + 8 + j;
      v1a[j] = (k0 < 35) ? f2bf(W1[k0 * 64 + nn]) : (short)0;
      v1b[j] = (k1 < 35) ? f2bf(W1[k1 * 64 + nn]) : (short)0;
      v2a[j] = f2bf(W2[k0 * 64 + nn]);
      v2b[j] = f2bf(W2[k1 * 64 + nn]);
    }
    int wo = nn * ROWS + kg * 16;
    *(bf16x8*)&W1T[wo]     = v1a;
    *(bf16x8*)&W1T[wo + 8] = v1b;
    *(bf16x8*)&W2T[wo]     = v2a;
    *(bf16x8*)&W2T[wo + 8] = v2b;
  }
  __syncthreads();

  int wave = tid >> 6, lane = tid & 63;
  int q = lane >> 4, nl = lane & 15;

  float b1v[4], b2v[4], w3v[4];
  #pragma unroll
  for (int t4 = 0; t4 < 4; ++t4) {
    b1v[t4] = b1[t4 * 16 + nl];
    b2v[t4] = b2[t4 * 16 + nl];
    w3v[t4] = W3[t4 * 16 + nl];
  }
  float b3s = b3[0];

  int blockBase = blockIdx.x * RPB;

  for (int batch = 0; batch < RPB / 64; ++batch) {
    int base = blockBase + batch * 64 + wave * 16;

    // ---- stage A tile: lane handles ray (base+nl), cols q*16..q*16+15 ----
    {
      int rr = base + nl;
      int rc = rr < n ? rr : (n - 1);
      bf16x8 c0 = {0,0,0,0,0,0,0,0}, c1 = {0,0,0,0,0,0,0,0};
      if (q == 0) {
        c0[0] = f2bf(dirs[rc * 3 + 0]);
        c0[1] = f2bf(dirs[rc * 3 + 1]);
        c0[2] = f2bf(dirs[rc * 3 + 2]);
        unsigned u0 = ws[0 * (size_t)n + rc], u1 = ws[1 * (size_t)n + rc];
        unsigned u2 = ws[2 * (size_t)n + rc], u3 = ws[3 * (size_t)n + rc];
        unsigned u4 = ws[4 * (size_t)n + rc], u5 = ws[5 * (size_t)n + rc];
        unsigned u6 = ws[6 * (size_t)n + rc];
        c0[3] = lo16(u0); c0[4] = hi16(u0); c0[5] = lo16(u1); c0[6] = hi16(u1);
        c0[7] = lo16(u2);
        c1[0] = hi16(u2); c1[1] = lo16(u3); c1[2] = hi16(u3); c1[3] = lo16(u4);
        c1[4] = hi16(u4); c1[5] = lo16(u5); c1[6] = hi16(u5); c1[7] = lo16(u6);
      } else if (q == 1) {
        unsigned u6  = ws[6  * (size_t)n + rc], u7  = ws[7  * (size_t)n + rc];
        unsigned u8  = ws[8  * (size_t)n + rc], u9  = ws[9  * (size_t)n + rc];
        unsigned u10 = ws[10 * (size_t)n + rc], u11 = ws[11 * (size_t)n + rc];
        unsigned u12 = ws[12 * (size_t)n + rc], u13 = ws[13 * (size_t)n + rc];
        unsigned u14 = ws[14 * (size_t)n + rc];
        c0[0] = hi16(u6);  c0[1] = lo16(u7);  c0[2] = hi16(u7);  c0[3] = lo16(u8);
        c0[4] = hi16(u8);  c0[5] = lo16(u9);  c0[6] = hi16(u9);  c0[7] = lo16(u10);
        c1[0] = hi16(u10); c1[1] = lo16(u11); c1[2] = hi16(u11); c1[3] = lo16(u12);
        c1[4] = hi16(u12); c1[5] = lo16(u13); c1[6] = hi16(u13); c1[7] = lo16(u14);
      } else if (q == 2) {
        unsigned u14 = ws[14 * (size_t)n + rc], u15 = ws[15 * (size_t)n + rc];
        c0[0] = hi16(u14); c0[1] = lo16(u15); c0[2] = hi16(u15);
      }
      int ao = nl * ROWS + q * 16;
      *(bf16x8*)&AT[wave][ao]     = c0;
      *(bf16x8*)&AT[wave][ao + 8] = c1;
    }
    __syncthreads();   // A-tile visible to all lanes (fences compiler too)

    // ---- layer 1: C = A(16x64) * W1(64->64) ----
    bf16x8 a0 = *(const bf16x8*)&AT[wave][nl * ROWS + q * 8];
    bf16x8 a1 = *(const bf16x8*)&AT[wave][nl * ROWS + 32 + q * 8];
    f32x4 acc[4];
    #pragma unroll
    for (int t4 = 0; t4 < 4; ++t4) {
      int brow = (t4 * 16 + nl) * ROWS;
      bf16x8 bt0 = *(const bf16x8*)&W1T[brow + q * 8];
      bf16x8 bt1 = *(const bf16x8*)&W1T[brow + 32 + q * 8];
      f32x4 z = {0.f, 0.f, 0.f, 0.f};
      z = __builtin_amdgcn_mfma_f32_16x16x32_bf16(a0, bt0, z, 0, 0, 0);
      z = __builtin_amdgcn_mfma_f32_16x16x32_bf16(a1, bt1, z, 0, 0, 0);
      acc[t4] = z;
    }
    // bias + relu -> H1 tile (C layout: row=q*4+i, col=t4*16+nl)
    #pragma unroll
    for (int t4 = 0; t4 < 4; ++t4)
      #pragma unroll
      for (int i = 0; i < 4; ++i) {
        float v = fmaxf(acc[t4][i] + b1v[t4], 0.0f);
        H1T[wave][(q * 4 + i) * ROWS + t4 * 16 + nl] = f2bf(v);
      }
    __syncthreads();   // H1 visible

    // ---- layer 2 ----
    a0 = *(const bf16x8*)&H1T[wave][nl * ROWS + q * 8];
    a1 = *(const bf16x8*)&H1T[wave][nl * ROWS + 32 + q * 8];
    #pragma unroll
    for (int t4 = 0; t4 < 4; ++t4) {
      int brow = (t4 * 16 + nl) * ROWS;
      bf16x8 bt0 = *(const bf16x8*)&W2T[brow + q * 8];
      bf16x8 bt1 = *(const bf16x8*)&W2T[brow + 32 + q * 8];
      f32x4 z = {0.f, 0.f, 0.f, 0.f};
      z = __builtin_amdgcn_mfma_f32_16x16x32_bf16(a0, bt0, z, 0, 0, 0);
      z = __builtin_amdgcn_mfma_f32_16x16x32_bf16(a1, bt1, z, 0, 0, 0);
      acc[t4] = z;
    }

    // ---- layer 3 (fp32): out[ray] = softplus(sum_n W3[n]*relu(c2+b2)+b3+1) ----
    float part[4] = {0.f, 0.f, 0.f, 0.f};
    #pragma unroll
    for (int t4 = 0; t4 < 4; ++t4)
      #pragma unroll
      for (int i = 0; i < 4; ++i) {
        float v = fmaxf(acc[t4][i] + b2v[t4], 0.0f);
        part[i] = fmaf(v, w3v[t4], part[i]);
      }
    #pragma unroll
    for (int s = 1; s < 16; s <<= 1) {
      #pragma unroll
      for (int i = 0; i < 4; ++i) part[i] += __shfl_xor(part[i], s, 64);
    }
    if (nl == 0) {
      int orow = base + q * 4;
      float ov[4];
      #pragma unroll
      for (int i = 0; i < 4; ++i) {
        float v = part[i] + b3s + 1.0f;
        ov[i] = fmaxf(v, 0.0f) + log1pf(expf(-fabsf(v)));   // softplus
      }
      if (orow + 3 < n) {
        float4 o4; o4.x = ov[0]; o4.y = ov[1]; o4.z = ov[2]; o4.w = ov[3];
        *(float4*)&out[orow] = o4;
      } else {
        for (int i = 0; i < 4; ++i) if (orow + i < n) out[orow + i] = ov[i];
      }
    }
    __syncthreads();   // WAR: next batch's AT/H1T staging must not pass reads
  }
}

// ============ Fallback: round-1 fused kernel (if ws too small) ==============
__global__ __launch_bounds__(256)
void sdf_fused(const float* __restrict__ dirs,
               const float* __restrict__ table,
               const float* __restrict__ W1, const float* __restrict__ b1,
               const float* __restrict__ W2, const float* __restrict__ b2,
               const float* __restrict__ W3, const float* __restrict__ b3,
               float* __restrict__ out, int n, LevelParams lp)
{
  int gid = blockIdx.x * 256 + threadIdx.x;
  if (gid >= n) return;
  float dx = dirs[gid * 3 + 0], dy = dirs[gid * 3 + 1], dz = dirs[gid * 3 + 2];
  float xx = dx * 0.49f + 0.49f, xy = dy * 0.49f + 0.49f, xz = dz * 0.49f + 0.49f;
  float h[35];
  h[0] = dx; h[1] = dy; h[2] = dz;
  #pragma unroll
  for (int l = 0; l < NL; ++l) {
    float s = lp.scale[l];
    float px = xx * s + 0.5f, py = xy * s + 0.5f, pz = xz * s + 0.5f;
    float gx = floorf(px), gy = floorf(py), gz = floorf(pz);
    float fx = px - gx, fy = py - gy, fz = pz - gz;
    unsigned ix = (unsigned)gx, iy = (unsigned)gy, iz = (unsigned)gz;
    float wx1 = fx * fx * (3.0f - 2.0f * fx);
    float wy1 = fy * fy * (3.0f - 2.0f * fy);
    float wz1 = fz * fz * (3.0f - 2.0f * fz);
    float wx0 = 1.0f - wx1, wy0 = 1.0f - wy1, wz0 = 1.0f - wz1;
    unsigned i000, i100, i010, i110, i001, i101, i011, i111;
    if ((lp.dense_mask >> l) & 1u) {
      unsigned r = lp.res[l], r2 = r * r;
      unsigned x0 = ix, x1 = ix + 1u, y0 = iy * r, y1 = y0 + r, z0 = iz * r2, z1 = z0 + r2;
      i000 = x0 + y0 + z0; i100 = x1 + y0 + z0; i010 = x0 + y1 + z0; i110 = x1 + y1 + z0;
      i001 = x0 + y0 + z1; i101 = x1 + y0 + z1; i011 = x0 + y1 + z1; i111 = x1 + y1 + z1;
    } else {
      unsigned x0 = ix, x1 = ix + 1u;
      unsigned y0 = iy * 2654435761u, y1 = y0 + 2654435761u;
      unsigned z0 = iz * 805459861u,  z1 = z0 + 805459861u;
      i000 = (x0 ^ y0 ^ z0) & TMASK; i100 = (x1 ^ y0 ^ z0) & TMASK;
      i010 = (x0 ^ y1 ^ z0) & TMASK; i110 = (x1 ^ y1 ^ z0) & TMASK;
      i001 = (x0 ^ y0 ^ z1) & TMASK; i101 = (x1 ^ y0 ^ z1) & TMASK;
      i011 = (x0 ^ y1 ^ z1) & TMASK; i111 = (x1 ^ y1 ^ z1) & TMASK;
    }
    const float2* t = (const float2*)table + (size_t)l * TSIZE;
    float2 f000 = t[i000], f100 = t[i100], f010 = t[i010], f110 = t[i110];
    float2 f001 = t[i001], f101 = t[i101], f011 = t[i011], f111 = t[i111];
    float wy0z0 = wy0 * wz0, wy1z0 = wy1 * wz0, wy0z1 = wy0 * wz1, wy1z1 = wy1 * wz1;
    float w000 = wx0 * wy0z0, w100 = wx1 * wy0z0, w010 = wx0 * wy1z0, w110 = wx1 * wy1z0;
    float w001 = wx0 * wy0z1, w101 = wx1 * wy0z1, w011 = wx0 * wy1z1, w111 = wx1 * wy1z1;
    h[3 + 2 * l] = w000 * f000.x + w100 * f100.x + w010 * f010.x + w110 * f110.x
                 + w001 * f001.x + w101 * f101.x + w011 * f011.x + w111 * f111.x;
    h[4 + 2 * l] = w000 * f000.y + w100 * f100.y + w010 * f010.y + w110 * f110.y
                 + w001 * f001.y + w101 * f101.y + w011 * f011.y + w111 * f111.y;
  }
  float h1[64];
  #pragma unroll
  for (int j = 0; j < 64; ++j) {
    float acc = b1[j];
    #pragma unroll
    for (int i = 0; i < 35; ++i) acc = fmaf(h[i], W1[i * 64 + j], acc);
    h1[j] = fmaxf(acc, 0.0f);
  }
  float h2[64];
  #pragma unroll
  for (int j = 0; j < 64; ++j) {
    float acc = b2[j];
    #pragma unroll
    for (int i = 0; i < 64; ++i) acc = fmaf(h1[i], W2[i * 64 + j], acc);
    h2[j] = fmaxf(acc, 0.0f);
  }
  float o = b3[0];
  #pragma unroll
  for (int i = 0; i < 64; ++i) o = fmaf(h2[i], W3[i], o);
  float v = o + 1.0f;
  out[gid] = fmaxf(v, 0.0f) + log1pf(expf(-fabsf(v)));
}

extern "C" void kernel_launch(void* const* d_in, const int* in_sizes, int n_in,
                              void* d_out, int out_size, void* d_ws, size_t ws_size,
                              hipStream_t stream) {
  const float* dirs  = (const float*)d_in[0];
  const float* table = (const float*)d_in[1];
  const float* W1 = (const float*)d_in[2];
  const float* b1 = (const float*)d_in[3];
  const float* W2 = (const float*)d_in[4];
  const float* b2 = (const float*)d_in[5];
  const float* W3 = (const float*)d_in[6];
  const float* b3 = (const float*)d_in[7];
  float* out = (float*)d_out;
  int n = in_sizes[0] / 3;

  LevelParams lp;
  double pls = std::exp(std::log(2048.0 / 16.0) / 15.0);
  unsigned dm = 0;
  for (int l = 0; l < NL; ++l) {
    double scale = 16.0 * std::pow(pls, (double)l) - 1.0;
    lp.scale[l] = (float)scale;
    long long res = (long long)std::ceil(scale) + 1;
    lp.res[l] = (unsigned)res;
    if (res * res * res <= (long long)TSIZE) dm |= (1u << l);
  }
  lp.dense_mask = dm;

  size_t feat_bytes = (size_t)n * NL * 4;  // 128 MiB at n=2M
  if (ws_size >= feat_bytes) {
    unsigned* feats = (unsigned*)d_ws;
    int chunks = (n + 255) / 256;
    hipLaunchKernelGGL(encode_k2, dim3(16 * chunks), dim3(256), 0, stream,
                       dirs, table, feats, n, lp);
    int mlp_blocks = (n + RPB - 1) / RPB;
    hipLaunchKernelGGL(mlp_mfma, dim3(mlp_blocks), dim3(256), 0, stream,
                       dirs, feats, W1, b1, W2, b2, W3, b3, out, n);
  } else {
    int blocks = (n + 255) / 256;
    hipLaunchKernelGGL(sdf_fused, dim3(blocks), dim3(256), 0, stream,
                       dirs, table, W1, b1, W2, b2, W3, b3, out, n, lp);
  }
}